// Round 11
// baseline (62.618 us; speedup 1.0000x reference)
//
#include <hip/hip_runtime.h>
#include <hip/hip_bf16.h>
#include <math.h>

#define KN 20
#define DD 64
#define WPB 4
#define NUSERS 100000
#define NITEMS 50000
#define NBU 1024   // blocks assigned to user table
#define NBI 512    // blocks assigned to item table
#define NBS 128    // score-convert blocks (only when ws is big enough)
#define SROW 24    // padded bf16 score row stride (48B, 16B-aligned, zeros 20..23)

typedef __hip_bfloat16 bf16;
typedef __attribute__((ext_vector_type(8))) short short8;   // 8 bf16 (4 VGPRs)
typedef __attribute__((ext_vector_type(16))) float f32x16;  // MFMA 32x32 acc

__device__ inline ushort f2bf(float f) {                    // fp32 -> bf16 RNE
    unsigned u = __builtin_bit_cast(unsigned, f);
    u += 0x7fffu + ((u >> 16) & 1u);
    return (ushort)(u >> 16);
}

// ====== precompute: Y = emb @ W1part; w2 -> frag table; scores -> bf16 ========
__global__ __launch_bounds__(256, 4) void precompute_Y(
    const float* __restrict__ emb_u, const float* __restrict__ emb_i,
    const float* __restrict__ w1, const float* __restrict__ w2,
    const float* __restrict__ uscr, const float* __restrict__ iscr,
    bf16* __restrict__ Yu, bf16* __restrict__ Yi, ushort* __restrict__ w2b,
    ushort* __restrict__ sbu, ushort* __restrict__ sbi)
{
    __shared__ float stage[WPB][256];
    const int w    = threadIdx.x >> 6;
    const int lane = threadIdx.x & 63;

    // ---- score tables -> bf16, chunk-parallel (1 thread = one 16B out chunk) --
    // R10's per-row scalar version was uncoalesced (3M dword loads, ~1 useful
    // load/cacheline). Chunk c: row r=c/3, part=c%3; 2 aligned float4 loads
    // (80r+32*part bytes, 16B-aligned) + one short8 store.
    if ((int)blockIdx.x >= NBU + NBI) {
        const int t0 = ((int)blockIdx.x - (NBU + NBI)) * 256 + (int)threadIdx.x;
        const int NCH = 3 * (NUSERS + NITEMS);
        for (int cch = t0; cch < NCH; cch += NBS * 256) {
            int r = cch / 3, part = cch - 3 * r;
            const float* src = (r < NUSERS) ? (uscr + (size_t)r * KN)
                                            : (iscr + (size_t)(r - NUSERS) * KN);
            ushort* dst = (r < NUSERS) ? (sbu + (size_t)r * SROW)
                                       : (sbi + (size_t)(r - NUSERS) * SROW);
            ushort tmp[8];
            if (part < 2) {
                float4 v0 = *(const float4*)(src + 8 * part);
                float4 v1 = *(const float4*)(src + 8 * part + 4);
                tmp[0] = f2bf(v0.x); tmp[1] = f2bf(v0.y);
                tmp[2] = f2bf(v0.z); tmp[3] = f2bf(v0.w);
                tmp[4] = f2bf(v1.x); tmp[5] = f2bf(v1.y);
                tmp[6] = f2bf(v1.z); tmp[7] = f2bf(v1.w);
            } else {
                float4 v0 = *(const float4*)(src + 16);
                tmp[0] = f2bf(v0.x); tmp[1] = f2bf(v0.y);
                tmp[2] = f2bf(v0.z); tmp[3] = f2bf(v0.w);
                tmp[4] = tmp[5] = tmp[6] = tmp[7] = 0;
            }
            *(short8*)(dst + 8 * part) = *(const short8*)tmp;
        }
        return;
    }

    // ---- w2 -> MFMA-B fragment order (one block) ----
    if ((int)blockIdx.x == NBU + NBI - 1) {
        const int tid = threadIdx.x;
        const int t = tid >> 6, gg = (tid >> 5) & 1, o = tid & 31;
        #pragma unroll
        for (int j = 0; j < 8; ++j)
            w2b[(size_t)tid * 8 + j] = f2bf(w2[(16 * t + 8 * gg + j) * 32 + o]);
    }

    const bool isU = (int)blockIdx.x < NBU;
    const float* __restrict__ emb  = isU ? emb_u : emb_i;
    bf16* __restrict__       Y     = isU ? Yu : Yi;
    const float* __restrict__ wsrc = isU ? w1 : (w1 + 64 * DD);
    const int ngroups = (isU ? NUSERS : NITEMS) / 4;
    const int bidx    = isU ? (int)blockIdx.x : ((int)blockIdx.x - NBU);
    const int nwaves  = (isU ? NBU : NBI) * WPB;
    const int wid     = bidx * WPB + w;

    float wreg[64];
    #pragma unroll
    for (int c = 0; c < 64; ++c) wreg[c] = wsrc[c * DD + lane];

    for (int g = wid; g < ngroups; g += nwaves) {
        float4 v = *(const float4*)&emb[(size_t)g * 256 + lane * 4];
        *(float4*)&stage[w][lane * 4] = v;
        #pragma unroll
        for (int r = 0; r < 4; ++r) {
            float a0 = 0.f, a1 = 0.f, a2 = 0.f, a3 = 0.f;
            #pragma unroll
            for (int q = 0; q < 16; ++q) {
                float4 e4 = *(const float4*)&stage[w][r * 64 + q * 4];
                a0 = fmaf(e4.x, wreg[q * 4 + 0], a0);
                a1 = fmaf(e4.y, wreg[q * 4 + 1], a1);
                a2 = fmaf(e4.z, wreg[q * 4 + 2], a2);
                a3 = fmaf(e4.w, wreg[q * 4 + 3], a3);
            }
            Y[(size_t)(g * 4 + r) * DD + lane] = (bf16)((a0 + a1) + (a2 + a3));
        }
    }
}

// ================= main fused kernel ==========================================
// GEMM1 on MFMA (R8/R9 verified layouts); Y rows staged via wave-private LDS;
// B-frags = ds_read_u16 w/ offset immediates; A-frags = direct 16B loads from
// pre-converted bf16 score tables (SBF). h1 (bf16, XOR-swizzled) unions into
// the user staging region; all LDS wave-private -> barrier-free.
// (256,8): VGPR demand measured 48 < 64-cap -> no spill (R4/R5 spilled at
// demand ~100); LDS 24KB -> 6 blocks/CU -> occupancy ceiling ~75%.
template<bool SBF>
__global__ __launch_bounds__(256, 8) void cnn_main(
    const int* __restrict__ user_idxs, const int* __restrict__ item_idxs,
    const int* __restrict__ user_idx_tensor, const float* __restrict__ uscr_f,
    const ushort* __restrict__ uscr_b,
    const int* __restrict__ item_idx_tensor, const float* __restrict__ iscr_f,
    const ushort* __restrict__ iscr_b,
    const bf16* __restrict__ Yu, const bf16* __restrict__ Yi,
    const float* __restrict__ b1, const ushort* __restrict__ w2b,
    const float* __restrict__ b2,
    const float* __restrict__ w3, const float* __restrict__ b3,
    float* __restrict__ out, int Bn)
{
    __shared__ ushort buf[WPB][3072];  // [side][24][64] staging; h1 reuses [0..1280)

    const int w    = threadIdx.x >> 6;
    const int lane = threadIdx.x & 63;
    const int g    = lane >> 5;            // half-wave group (k-octet select)
    const int c    = lane & 31;            // tile column / row index
    const int b = blockIdx.x * WPB + w;
    if (b >= Bn) return;                   // no barriers -> divergence-safe

    const int uid = user_idxs[b];
    const int iid = item_idxs[b];

    int nvu = 0, nvi = 0;
    if (lane < KN) {
        nvu = user_idx_tensor[uid * KN + lane];
        nvi = item_idx_tensor[iid * KN + lane];
    }

    // ---- stage Y rows (both sides) into wave-private LDS, coalesced ----
    #pragma unroll
    for (int side = 0; side < 2; ++side) {
        const ushort* Y = (const ushort*)(side ? Yi : Yu);
        const int nv = side ? nvi : nvu;
        #pragma unroll
        for (int i = 0; i < 3; ++i) {                 // rows 8i..8i+7 (16..23 pad junk)
            int nr = __shfl(nv, 8 * i + (lane >> 3)); // lanes>=KN give nv=0: safe
            short8 v = *(const short8*)(Y + (size_t)nr * DD + (lane & 7) * 8);
            *(short8*)&buf[w][side * 1536 + i * 512 + lane * 8] = v;
        }
    }

    f32x16 acc0 = {};   // h1 cols 0..31
    f32x16 acc1 = {};   // h1 cols 32..63

    #pragma unroll
    for (int side = 0; side < 2; ++side) {
        const int nv = side ? nvi : nvu;
        const int n_r = __shfl(nv, c);

        // ---- A frags: score row (l&31), k-octet 8g+j ----
        short8 A0, A1;
        if (SBF) {
            const ushort* sr = (side ? iscr_b : uscr_b) + (size_t)n_r * SROW;
            A0 = *(const short8*)(sr + 8 * g);     // k 8g..8g+7
            A1 = *(const short8*)(sr + 16);        // k 16..23 (20..23 are zeros)
        } else {
            const float* arow = (side ? iscr_f : uscr_f) + (size_t)n_r * KN;
            float4 a0 = *(const float4*)(arow + 8 * g);
            float4 a1 = *(const float4*)(arow + 8 * g + 4);
            A0[0] = (short)f2bf(a0.x); A0[1] = (short)f2bf(a0.y);
            A0[2] = (short)f2bf(a0.z); A0[3] = (short)f2bf(a0.w);
            A0[4] = (short)f2bf(a1.x); A0[5] = (short)f2bf(a1.y);
            A0[6] = (short)f2bf(a1.z); A0[7] = (short)f2bf(a1.w);
            float4 a2 = *(const float4*)(arow + 16);
            A1 = short8{};
            A1[0] = (short)f2bf(a2.x); A1[1] = (short)f2bf(a2.y);
            A1[2] = (short)f2bf(a2.z); A1[3] = (short)f2bf(a2.w);
        }

        // ---- B frags from LDS (base reg + offset immediates) ----
        const int sb0 = side * 1536;
        short8 B00, B01;
        #pragma unroll
        for (int j = 0; j < 8; ++j) {
            B00[j] = (short)buf[w][sb0 + (8 * g + j) * DD + c];
            B01[j] = (short)buf[w][sb0 + (8 * g + j) * DD + 32 + c];
        }
        acc0 = __builtin_amdgcn_mfma_f32_32x32x16_bf16(A0, B00, acc0, 0, 0, 0);
        acc1 = __builtin_amdgcn_mfma_f32_32x32x16_bf16(A0, B01, acc1, 0, 0, 0);

        short8 B10 = {}, B11 = {};
        if (g == 0) {                                  // rows 16..19; g1 keeps zeros
            #pragma unroll
            for (int j = 0; j < 4; ++j) {
                B10[j] = (short)buf[w][sb0 + (16 + j) * DD + c];
                B11[j] = (short)buf[w][sb0 + (16 + j) * DD + 32 + c];
            }
        }
        acc0 = __builtin_amdgcn_mfma_f32_32x32x16_bf16(A1, B10, acc0, 0, 0, 0);
        acc1 = __builtin_amdgcn_mfma_f32_32x32x16_bf16(A1, B11, acc1, 0, 0, 0);
    }

    // ---- bias + relu -> bf16 -> swizzled LDS rows<20 (reuses [0..1280)) ----
    const float b1v0 = b1[c];
    const float b1v1 = b1[32 + c];
    #pragma unroll
    for (int r = 0; r < 12; ++r) {
        const int row = (r & 3) + 8 * (r >> 2) + 4 * g;
        if (row < KN) {
            const int ch0 = (c >> 3) ^ (row & 7);
            const int ch1 = (4 + (c >> 3)) ^ (row & 7);
            buf[w][row * DD + ch0 * 8 + (c & 7)] = f2bf(fmaxf(acc0[r] + b1v0, 0.f));
            buf[w][row * DD + ch1 * 8 + (c & 7)] = f2bf(fmaxf(acc1[r] + b1v1, 0.f));
        }
    }

    // ---- layer2 MFMA: h2(20x32) = h1(20x64) @ w2(64x32), 4 K-steps ----
    const int ar = (c < KN) ? c : 0;       // clamp A row (rows>=20 don't-care)
    f32x16 c2 = {};
    #pragma unroll
    for (int t = 0; t < 4; ++t) {
        const int chunk = (2 * t + g) ^ (ar & 7);
        short8 A = *(const short8*)&buf[w][ar * DD + chunk * 8];
        short8 B = *(const short8*)&w2b[(size_t)(((t * 2 + g) * 32 + c)) * 8];
        c2 = __builtin_amdgcn_mfma_f32_32x32x16_bf16(A, B, c2, 0, 0, 0);
    }

    // ---- layer3: bias+relu, *w3, butterfly over 32 cols, sigmoid, mean ----
    const float b2v = b2[c];
    const float w3v = w3[c];
    const float b3v = b3[0];
    float sum = 0.f;
    #pragma unroll
    for (int r = 0; r < 12; ++r) {
        float h2v = fmaxf(c2[r] + b2v, 0.f);
        float p = h2v * w3v;
        #pragma unroll
        for (int off = 16; off > 0; off >>= 1)
            p += __shfl_xor(p, off);               // sum over 32 out-cols
        float logit = p + b3v;
        if (g == 0 || r < 8)                       // valid rows: g0 12, g1 8 (=20)
            sum += 1.f / (1.f + __expf(-logit));
    }
    sum += __shfl_xor(sum, 32);
    if (lane == 0) out[b] = sum * (1.f / KN);
}

extern "C" void kernel_launch(void* const* d_in, const int* in_sizes, int n_in,
                              void* d_out, int out_size, void* d_ws, size_t ws_size,
                              hipStream_t stream) {
    const int*   user_idxs       = (const int*)  d_in[0];
    const int*   item_idxs       = (const int*)  d_in[1];
    const int*   user_idx_tensor = (const int*)  d_in[2];
    const float* user_scr_tensor = (const float*)d_in[3];
    const int*   item_idx_tensor = (const int*)  d_in[4];
    const float* item_scr_tensor = (const float*)d_in[5];
    const float* user_emb        = (const float*)d_in[6];
    const float* item_emb        = (const float*)d_in[7];
    const float* w1 = (const float*)d_in[8];
    const float* b1 = (const float*)d_in[9];
    const float* w2 = (const float*)d_in[10];
    const float* b2 = (const float*)d_in[11];
    const float* w3 = (const float*)d_in[12];
    const float* b3 = (const float*)d_in[13];
    float* out = (float*)d_out;

    const int Bn = in_sizes[0];

    // ws: Yu bf16[100000*64] | Yi bf16[50000*64] | w2b u16[2048] | sbu | sbi
    bf16*   Yu  = (bf16*)d_ws;
    bf16*   Yi  = Yu + (size_t)NUSERS * DD;
    ushort* w2b = (ushort*)(Yi + (size_t)NITEMS * DD);
    ushort* sbu = w2b + 2048;
    ushort* sbi = sbu + (size_t)NUSERS * SROW;

    const size_t need = (size_t)(NUSERS + NITEMS) * DD * 2 + 2048 * 2
                      + (size_t)(NUSERS + NITEMS) * SROW * 2;
    const bool big = ws_size >= need;

    precompute_Y<<<NBU + NBI + (big ? NBS : 0), 256, 0, stream>>>(
        user_emb, item_emb, w1, w2, user_scr_tensor, item_scr_tensor,
        Yu, Yi, w2b, sbu, sbi);

    const int grid = (Bn + WPB - 1) / WPB;
    if (big)
        cnn_main<true><<<grid, 256, 0, stream>>>(
            user_idxs, item_idxs, user_idx_tensor, user_scr_tensor, sbu,
            item_idx_tensor, item_scr_tensor, sbi, Yu, Yi,
            b1, w2b, b2, w3, b3, out, Bn);
    else
        cnn_main<false><<<grid, 256, 0, stream>>>(
            user_idxs, item_idxs, user_idx_tensor, user_scr_tensor, sbu,
            item_idx_tensor, item_scr_tensor, sbi, Yu, Yi,
            b1, w2b, b2, w3, b3, out, Bn);
}